// Round 12
// baseline (615.891 us; speedup 1.0000x reference)
//
#include <hip/hip_runtime.h>
#include <math.h>

#define BB 4
#define NN 2048
#define DD 64
#define PP 8192
#define NSTRIPE 512
#define VV 32          // packed elements per lane; one wave64 per column-pair
#define GG 8           // projections per block

typedef unsigned int u32;
typedef _Float16 h2 __attribute__((ext_vector_type(2)));
typedef __fp16 fh8 __attribute__((ext_vector_type(8)));   // amdgcn builtins use __fp16 vecs (round-9 evidence)
typedef float f32x4 __attribute__((ext_vector_type(4)));
typedef u32 u32x4 __attribute__((ext_vector_type(4)));

__global__ void zero_ws_kernel(float* ws) {
    int t = blockIdx.x * blockDim.x + threadIdx.x;
    if (t < BB * NSTRIPE) ws[t] = 0.f;
}

// pack two f32 -> fp16x2 bits (v_cvt_pkrtz_f16_f32)
__device__ __forceinline__ u32 pk2u(float a, float b) {
    return __builtin_bit_cast(u32, __builtin_amdgcn_cvt_pkrtz(a, b));
}

__device__ __forceinline__ u32 pk_min(u32 a, u32 b) {
    h2 r = __builtin_elementwise_min(__builtin_bit_cast(h2, a), __builtin_bit_cast(h2, b));
    return __builtin_bit_cast(u32, r);
}
__device__ __forceinline__ u32 pk_max(u32 a, u32 b) {
    h2 r = __builtin_elementwise_max(__builtin_bit_cast(h2, a), __builtin_bit_cast(h2, b));
    return __builtin_bit_cast(u32, r);
}

// ascending compare-exchange (static): a=min, b=max
__device__ __forceinline__ void ceA(u32& a, u32& b) {
    u32 lo = pk_min(a, b), hi = pk_max(a, b);
    a = lo; b = hi;
}

// lane-xor fetch: ds_swizzle BitMode for masks <= 31, ds_bpermute for 63
template<int LM>
__device__ __forceinline__ u32 lxf(u32 x, int a63) {
    if constexpr (LM == 63) return (u32)__builtin_amdgcn_ds_bpermute(a63, (int)x);
    else                    return (u32)__builtin_amdgcn_ds_swizzle((int)x, 0x1F | (LM << 10));
}

// normalized bitonic sort of the 32 intra-lane elements (all static)
__device__ __forceinline__ void sortV(u32* e) {
    #pragma unroll
    for (int k = 2; k <= 32; k <<= 1) {
        #pragma unroll
        for (int v = 0; v < VV; v++) {
            int pv = v ^ (k - 1);
            if (v < pv) ceA(e[v], e[pv]);
        }
        #pragma unroll
        for (int j = k >> 2; j >= 1; j >>= 1)
            #pragma unroll
            for (int v = 0; v < VV; v++)
                if ((v & j) == 0) ceA(e[v], e[v | j]);
    }
}

// intra-lane cleaners j = 16..1 (static ascending)
__device__ __forceinline__ void clean16(u32* e) {
    #pragma unroll
    for (int j = 16; j >= 1; j >>= 1)
        #pragma unroll
        for (int v = 0; v < VV; v++)
            if ((v & j) == 0) ceA(e[v], e[v | j]);
}

// aligned cross pass: partner = same elem, lane ^ LM
template<int LM>
__device__ __forceinline__ void crossA(u32* e, bool keep, int a63) {
    #pragma unroll
    for (int v = 0; v < VV; v++) {
        u32 p = lxf<LM>(e[v], a63);
        e[v] = keep ? pk_min(e[v], p) : pk_max(e[v], p);
    }
}

template<int LM>
__device__ __forceinline__ void crossA_chain(u32* e, int lane, int a63) {
    crossA<LM>(e, (lane & LM) == 0, a63);
    if constexpr (LM > 1) crossA_chain<(LM >> 1)>(e, lane, a63);
}

// reflection cross pass: partner = elem v^31 at lane ^ LM
template<int LM>
__device__ __forceinline__ void crossR(u32* e, bool keep, int a63) {
    #pragma unroll
    for (int v = 0; v < 16; v++) {
        const int w2 = v ^ 31;
        u32 p1 = lxf<LM>(e[w2], a63);
        u32 p2 = lxf<LM>(e[v], a63);
        e[v]  = keep ? pk_min(e[v],  p1) : pk_max(e[v],  p1);
        e[w2] = keep ? pk_min(e[w2], p2) : pk_max(e[w2], p2);
    }
}

// merge level K (64..2048), fully in-wave
template<int K>
__device__ __forceinline__ void level(u32* e, int lane, int a63) {
    crossR<(K >> 5) - 1>(e, (lane & (K >> 6)) == 0, a63);
    if constexpr (K >= 128) crossA_chain<(K >> 7)>(e, lane, a63);
    clean16(e);
}

__global__ __launch_bounds__(256) void swd_kernel(const float* __restrict__ x,
                                                  const float* __restrict__ y,
                                                  const float* __restrict__ proj,
                                                  float* __restrict__ ws) {
    __shared__ __align__(16) u32 sbu[GG * NN];   // 64 KB: 8 columns of 2048 packed (x,y)

    const int tid = threadIdx.x;
    const int lane = tid & 63;
    const int w = tid >> 6;                    // wave id 0..3
    const int g16 = lane & 15;                 // MFMA n / m lane index
    const int kb = lane >> 4;                  // k-group 0..3
    const int blk = blockIdx.x;
    const int b = blk >> 10;                   // 1024 blocks per batch
    const int pbase = (blk & 1023) << 3;       // 8 proj rows per block

    // ---- B fragments (proj^T), k split kk=0 (dims 0..31) / kk=1 (dims 32..63)
    u32x4 bw0 = {0, 0, 0, 0}, bw1 = {0, 0, 0, 0};
    if (g16 < GG) {
        const float4* pr = (const float4*)(proj + (size_t)(pbase + g16) * DD);
        float4 f0 = pr[kb * 2], f1 = pr[kb * 2 + 1];
        bw0[0] = pk2u(f0.x, f0.y); bw0[1] = pk2u(f0.z, f0.w);
        bw0[2] = pk2u(f1.x, f1.y); bw0[3] = pk2u(f1.z, f1.w);
        float4 f2 = pr[8 + kb * 2], f3 = pr[8 + kb * 2 + 1];
        bw1[0] = pk2u(f2.x, f2.y); bw1[1] = pk2u(f2.z, f2.w);
        bw1[2] = pk2u(f3.x, f3.y); bw1[3] = pk2u(f3.z, f3.w);
    }
    const fh8 bf0 = __builtin_bit_cast(fh8, bw0);
    const fh8 bf1 = __builtin_bit_cast(fh8, bw1);

    const float* xb = x + (size_t)b * NN * DD;
    const float* yb = y + (size_t)b * NN * DD;

    // A-fragment loader: row = rowbase + (lane&15), dims kk*32 + kb*8 .. +7
    auto aload = [&](const float* base, int rowbase, int kk) -> fh8 {
        const float4* ar = (const float4*)(base + (size_t)(rowbase + g16) * DD) + kk * 8 + kb * 2;
        float4 a0 = ar[0], a1 = ar[1];
        u32x4 t;
        t[0] = pk2u(a0.x, a0.y); t[1] = pk2u(a0.z, a0.w);
        t[2] = pk2u(a1.x, a1.y); t[3] = pk2u(a1.z, a1.w);
        return __builtin_bit_cast(fh8, t);
    };

    // ---- projection via MFMA: wave w covers rows w*512 .. +511 of both arrays
    #pragma unroll 2
    for (int t = 0; t < 32; t++) {
        const int rowbase = (w << 9) + (t << 4);
        f32x4 accx = {0.f, 0.f, 0.f, 0.f};
        f32x4 accy = {0.f, 0.f, 0.f, 0.f};
        accx = __builtin_amdgcn_mfma_f32_16x16x32_f16(aload(xb, rowbase, 0), bf0, accx, 0, 0, 0);
        accx = __builtin_amdgcn_mfma_f32_16x16x32_f16(aload(xb, rowbase, 1), bf1, accx, 0, 0, 0);
        accy = __builtin_amdgcn_mfma_f32_16x16x32_f16(aload(yb, rowbase, 0), bf0, accy, 0, 0, 0);
        accy = __builtin_amdgcn_mfma_f32_16x16x32_f16(aload(yb, rowbase, 1), bf1, accy, 0, 0, 0);
        // C layout (m89-verified): col g = lane&15, row = rowbase + (lane>>4)*4 + r
        if (g16 < GG) {
            const int R0 = rowbase + (kb << 2);
            #pragma unroll
            for (int r = 0; r < 4; r++) {
                u32 pk = pk2u(accx[r], accy[r]);          // x -> lo, y -> hi
                sbu[(g16 << 11) + ((R0 + r) ^ (g16 << 2))] = pk;
            }
        }
    }
    __syncthreads();

    // ---- sort: wave w sorts column g = rnd*4 + w, fully wave-local (no barriers)
    const int a63 = (lane ^ 63) << 2;

    #pragma unroll 1
    for (int rnd = 0; rnd < 2; rnd++) {
        const int g = (rnd << 2) | w;
        const u32* colbase = sbu + (g << 11) + (lane << 5);

        u32 e[VV];
        #pragma unroll
        for (int vb = 0; vb < 8; vb++) {
            uint4 tq = *(const uint4*)(colbase + ((vb ^ g) << 2));
            e[vb * 4 + 0] = tq.x; e[vb * 4 + 1] = tq.y;
            e[vb * 4 + 2] = tq.z; e[vb * 4 + 3] = tq.w;
        }

        sortV(e);                              // k = 2..32 (intra-lane)
        level<64>(e, lane, a63);
        level<128>(e, lane, a63);
        level<256>(e, lane, a63);
        level<512>(e, lane, a63);
        level<1024>(e, lane, a63);
        level<2048>(e, lane, a63);

        // sum of squared diffs: lo = sorted x-col, hi = sorted y-col
        float s = 0.f;
        #pragma unroll
        for (int v = 0; v < VV; v++) {
            h2 h = __builtin_bit_cast(h2, e[v]);
            float d = (float)h[0] - (float)h[1];
            s += d * d;
        }
        #pragma unroll
        for (int off = 32; off > 0; off >>= 1)
            s += __shfl_down(s, off, 64);
        if (lane == 0)
            atomicAdd(&ws[b * NSTRIPE + ((pbase + g) & (NSTRIPE - 1))], s);
    }
}

__global__ void finalize_kernel(const float* __restrict__ ws, float* __restrict__ out) {
    __shared__ float red[256];
    int tid = threadIdx.x;
    for (int b = 0; b < BB; b++) {
        float s = 0.f;
        for (int i = tid; i < NSTRIPE; i += 256) s += ws[b * NSTRIPE + i];
        red[tid] = s;
        __syncthreads();
        for (int o = 128; o > 0; o >>= 1) {
            if (tid < o) red[tid] += red[tid + o];
            __syncthreads();
        }
        if (tid == 0) {
            float swd = red[0] / ((float)NN * (float)PP);
            out[b] = expf(-swd * swd * 0.5f);
        }
        __syncthreads();
    }
}

extern "C" void kernel_launch(void* const* d_in, const int* in_sizes, int n_in,
                              void* d_out, int out_size, void* d_ws, size_t ws_size,
                              hipStream_t stream) {
    const float* x = (const float*)d_in[0];
    const float* y = (const float*)d_in[1];
    const float* proj = (const float*)d_in[2];
    float* out = (float*)d_out;
    float* ws = (float*)d_ws;

    zero_ws_kernel<<<(BB * NSTRIPE + 255) / 256, 256, 0, stream>>>(ws);
    swd_kernel<<<BB * PP / GG, 256, 0, stream>>>(x, y, proj, ws);
    finalize_kernel<<<1, 256, 0, stream>>>(ws, out);
}

// Round 13
// 510.115 us; speedup vs baseline: 1.2074x; 1.2074x over previous
//
#include <hip/hip_runtime.h>
#include <math.h>

#define BB 4
#define NN 2048
#define DD 64
#define PP 8192
#define NSTRIPE 512
#define VV 32          // packed elements per lane; one wave64 per column-pair
#define GG 8           // projections per block

typedef unsigned int u32;
typedef _Float16 h2 __attribute__((ext_vector_type(2)));
typedef __fp16 fh8 __attribute__((ext_vector_type(8)));
typedef float f32x4 __attribute__((ext_vector_type(4)));
typedef u32 u32x4 __attribute__((ext_vector_type(4)));

__global__ void zero_ws_kernel(float* ws) {
    int t = blockIdx.x * blockDim.x + threadIdx.x;
    if (t < BB * NSTRIPE) ws[t] = 0.f;
}

__device__ __forceinline__ u32 pk2u(float a, float b) {
    return __builtin_bit_cast(u32, __builtin_amdgcn_cvt_pkrtz(a, b));
}

__device__ __forceinline__ u32 pk_min(u32 a, u32 b) {
    h2 r = __builtin_elementwise_min(__builtin_bit_cast(h2, a), __builtin_bit_cast(h2, b));
    return __builtin_bit_cast(u32, r);
}
__device__ __forceinline__ u32 pk_max(u32 a, u32 b) {
    h2 r = __builtin_elementwise_max(__builtin_bit_cast(h2, a), __builtin_bit_cast(h2, b));
    return __builtin_bit_cast(u32, r);
}

__device__ __forceinline__ void ceA(u32& a, u32& b) {
    u32 lo = pk_min(a, b), hi = pk_max(a, b);
    a = lo; b = hi;
}

// lane-xor fetch: ds_swizzle BitMode for masks <= 31, ds_bpermute for 63
template<int LM>
__device__ __forceinline__ u32 lxf(u32 x, int a63) {
    if constexpr (LM == 63) return (u32)__builtin_amdgcn_ds_bpermute(a63, (int)x);
    else                    return (u32)__builtin_amdgcn_ds_swizzle((int)x, 0x1F | (LM << 10));
}

// normalized bitonic sort of the 32 intra-lane elements (all static)
__device__ __forceinline__ void sortV(u32* e) {
    #pragma unroll
    for (int k = 2; k <= 32; k <<= 1) {
        #pragma unroll
        for (int v = 0; v < VV; v++) {
            int pv = v ^ (k - 1);
            if (v < pv) ceA(e[v], e[pv]);
        }
        #pragma unroll
        for (int j = k >> 2; j >= 1; j >>= 1)
            #pragma unroll
            for (int v = 0; v < VV; v++)
                if ((v & j) == 0) ceA(e[v], e[v | j]);
    }
}

__device__ __forceinline__ void clean16(u32* e) {
    #pragma unroll
    for (int j = 16; j >= 1; j >>= 1)
        #pragma unroll
        for (int v = 0; v < VV; v++)
            if ((v & j) == 0) ceA(e[v], e[v | j]);
}

template<int LM>
__device__ __forceinline__ void crossA(u32* e, bool keep, int a63) {
    #pragma unroll
    for (int v = 0; v < VV; v++) {
        u32 p = lxf<LM>(e[v], a63);
        e[v] = keep ? pk_min(e[v], p) : pk_max(e[v], p);
    }
}

template<int LM>
__device__ __forceinline__ void crossA_chain(u32* e, int lane, int a63) {
    crossA<LM>(e, (lane & LM) == 0, a63);
    if constexpr (LM > 1) crossA_chain<(LM >> 1)>(e, lane, a63);
}

template<int LM>
__device__ __forceinline__ void crossR(u32* e, bool keep, int a63) {
    #pragma unroll
    for (int v = 0; v < 16; v++) {
        const int w2 = v ^ 31;
        u32 p1 = lxf<LM>(e[w2], a63);
        u32 p2 = lxf<LM>(e[v], a63);
        e[v]  = keep ? pk_min(e[v],  p1) : pk_max(e[v],  p1);
        e[w2] = keep ? pk_min(e[w2], p2) : pk_max(e[w2], p2);
    }
}

template<int K>
__device__ __forceinline__ void level(u32* e, int lane, int a63) {
    crossR<(K >> 5) - 1>(e, (lane & (K >> 6)) == 0, a63);
    if constexpr (K >= 128) crossA_chain<(K >> 7)>(e, lane, a63);
    clean16(e);
}

__global__ __launch_bounds__(512) void swd_kernel(const float* __restrict__ x,
                                                  const float* __restrict__ y,
                                                  const float* __restrict__ proj,
                                                  float* __restrict__ ws) {
    __shared__ __align__(16) u32 sbu[GG * NN];   // 64 KB: 8 columns of 2048 packed (x,y)

    const int tid = threadIdx.x;
    const int lane = tid & 63;
    const int w = tid >> 6;                    // wave id 0..7
    const int g16 = lane & 15;                 // MFMA n / m lane index
    const int kb = lane >> 4;                  // k-group 0..3
    const int blk = blockIdx.x;
    const int b = blk >> 10;                   // 1024 blocks per batch
    const int pbase = (blk & 1023) << 3;       // 8 proj rows per block

    // ---- B fragments (proj^T), k split kk=0 (dims 0..31) / kk=1 (dims 32..63)
    u32x4 bw0 = {0, 0, 0, 0}, bw1 = {0, 0, 0, 0};
    if (g16 < GG) {
        const float4* pr = (const float4*)(proj + (size_t)(pbase + g16) * DD);
        float4 f0 = pr[kb * 2], f1 = pr[kb * 2 + 1];
        bw0[0] = pk2u(f0.x, f0.y); bw0[1] = pk2u(f0.z, f0.w);
        bw0[2] = pk2u(f1.x, f1.y); bw0[3] = pk2u(f1.z, f1.w);
        float4 f2 = pr[8 + kb * 2], f3 = pr[8 + kb * 2 + 1];
        bw1[0] = pk2u(f2.x, f2.y); bw1[1] = pk2u(f2.z, f2.w);
        bw1[2] = pk2u(f3.x, f3.y); bw1[3] = pk2u(f3.z, f3.w);
    }
    const fh8 bf0 = __builtin_bit_cast(fh8, bw0);
    const fh8 bf1 = __builtin_bit_cast(fh8, bw1);

    const float* xb = x + (size_t)b * NN * DD;
    const float* yb = y + (size_t)b * NN * DD;

    // A-fragment loader: row = rowbase + (lane&15), dims kk*32 + kb*8 .. +7
    auto aload = [&](const float* base, int rowbase, int kk) -> fh8 {
        const float4* ar = (const float4*)(base + (size_t)(rowbase + g16) * DD) + kk * 8 + kb * 2;
        float4 a0 = ar[0], a1 = ar[1];
        u32x4 t;
        t[0] = pk2u(a0.x, a0.y); t[1] = pk2u(a0.z, a0.w);
        t[2] = pk2u(a1.x, a1.y); t[3] = pk2u(a1.z, a1.w);
        return __builtin_bit_cast(fh8, t);
    };

    // ---- projection via MFMA: wave w covers rows w*256 .. +255 of both arrays
    #pragma unroll 2
    for (int t = 0; t < 16; t++) {
        const int rowbase = (w << 8) + (t << 4);
        f32x4 accx = {0.f, 0.f, 0.f, 0.f};
        f32x4 accy = {0.f, 0.f, 0.f, 0.f};
        accx = __builtin_amdgcn_mfma_f32_16x16x32_f16(aload(xb, rowbase, 0), bf0, accx, 0, 0, 0);
        accx = __builtin_amdgcn_mfma_f32_16x16x32_f16(aload(xb, rowbase, 1), bf1, accx, 0, 0, 0);
        accy = __builtin_amdgcn_mfma_f32_16x16x32_f16(aload(yb, rowbase, 0), bf0, accy, 0, 0, 0);
        accy = __builtin_amdgcn_mfma_f32_16x16x32_f16(aload(yb, rowbase, 1), bf1, accy, 0, 0, 0);
        // C layout (m89-verified): col g = lane&15, row = rowbase + (lane>>4)*4 + r
        if (g16 < GG) {
            const int R0 = rowbase + (kb << 2);
            #pragma unroll
            for (int r = 0; r < 4; r++) {
                u32 pk = pk2u(accx[r], accy[r]);          // x -> lo, y -> hi
                sbu[(g16 << 11) + ((R0 + r) ^ (g16 << 2))] = pk;
            }
        }
    }
    __syncthreads();

    // ---- sort: wave w sorts column g = w, fully wave-local (no barriers, no rounds)
    const int a63 = (lane ^ 63) << 2;
    const int g = w;
    const u32* colbase = sbu + (g << 11) + (lane << 5);

    u32 e[VV];
    #pragma unroll
    for (int vb = 0; vb < 8; vb++) {
        uint4 tq = *(const uint4*)(colbase + ((vb ^ g) << 2));
        e[vb * 4 + 0] = tq.x; e[vb * 4 + 1] = tq.y;
        e[vb * 4 + 2] = tq.z; e[vb * 4 + 3] = tq.w;
    }

    sortV(e);                              // k = 2..32 (intra-lane)
    level<64>(e, lane, a63);
    level<128>(e, lane, a63);
    level<256>(e, lane, a63);
    level<512>(e, lane, a63);
    level<1024>(e, lane, a63);
    level<2048>(e, lane, a63);

    // sum of squared diffs: lo = sorted x-col, hi = sorted y-col
    float s = 0.f;
    #pragma unroll
    for (int v = 0; v < VV; v++) {
        h2 h = __builtin_bit_cast(h2, e[v]);
        float d = (float)h[0] - (float)h[1];
        s += d * d;
    }
    #pragma unroll
    for (int off = 32; off > 0; off >>= 1)
        s += __shfl_down(s, off, 64);
    if (lane == 0)
        atomicAdd(&ws[b * NSTRIPE + ((pbase + g) & (NSTRIPE - 1))], s);
}

__global__ void finalize_kernel(const float* __restrict__ ws, float* __restrict__ out) {
    __shared__ float red[256];
    int tid = threadIdx.x;
    for (int b = 0; b < BB; b++) {
        float s = 0.f;
        for (int i = tid; i < NSTRIPE; i += 256) s += ws[b * NSTRIPE + i];
        red[tid] = s;
        __syncthreads();
        for (int o = 128; o > 0; o >>= 1) {
            if (tid < o) red[tid] += red[tid + o];
            __syncthreads();
        }
        if (tid == 0) {
            float swd = red[0] / ((float)NN * (float)PP);
            out[b] = expf(-swd * swd * 0.5f);
        }
        __syncthreads();
    }
}

extern "C" void kernel_launch(void* const* d_in, const int* in_sizes, int n_in,
                              void* d_out, int out_size, void* d_ws, size_t ws_size,
                              hipStream_t stream) {
    const float* x = (const float*)d_in[0];
    const float* y = (const float*)d_in[1];
    const float* proj = (const float*)d_in[2];
    float* out = (float*)d_out;
    float* ws = (float*)d_ws;

    zero_ws_kernel<<<(BB * NSTRIPE + 255) / 256, 256, 0, stream>>>(ws);
    swd_kernel<<<BB * PP / GG, 512, 0, stream>>>(x, y, proj, ws);
    finalize_kernel<<<1, 256, 0, stream>>>(ws, out);
}

// Round 14
// 495.291 us; speedup vs baseline: 1.2435x; 1.0299x over previous
//
#include <hip/hip_runtime.h>
#include <math.h>

#define BB 4
#define NN 2048
#define DD 64
#define PP 8192
#define NSTRIPE 512
#define VV 32          // packed elements per lane; one wave64 per column-pair
#define GG 8           // projections per block

typedef unsigned int u32;
typedef _Float16 h2 __attribute__((ext_vector_type(2)));
typedef __fp16 fh8 __attribute__((ext_vector_type(8)));
typedef float f32x4 __attribute__((ext_vector_type(4)));
typedef u32 u32x4 __attribute__((ext_vector_type(4)));

__global__ void zero_ws_kernel(float* ws) {
    int t = blockIdx.x * blockDim.x + threadIdx.x;
    if (t < BB * NSTRIPE) ws[t] = 0.f;
}

__device__ __forceinline__ u32 pk2u(float a, float b) {
    return __builtin_bit_cast(u32, __builtin_amdgcn_cvt_pkrtz(a, b));
}

__device__ __forceinline__ u32 pk_min(u32 a, u32 b) {
    h2 r = __builtin_elementwise_min(__builtin_bit_cast(h2, a), __builtin_bit_cast(h2, b));
    return __builtin_bit_cast(u32, r);
}
__device__ __forceinline__ u32 pk_max(u32 a, u32 b) {
    h2 r = __builtin_elementwise_max(__builtin_bit_cast(h2, a), __builtin_bit_cast(h2, b));
    return __builtin_bit_cast(u32, r);
}

__device__ __forceinline__ void ceA(u32& a, u32& b) {
    u32 lo = pk_min(a, b), hi = pk_max(a, b);
    a = lo; b = hi;
}

// lane-xor fetch. DPP (VALU pipe) for masks 1,2,3,7,8,15; ds_swizzle for 4,16,31; bpermute for 63.
template<int LM>
__device__ __forceinline__ u32 lxf(u32 x, int a63) {
    if constexpr (LM == 1)       return (u32)__builtin_amdgcn_update_dpp((int)x, (int)x, 0xB1, 0xF, 0xF, false);
    else if constexpr (LM == 2)  return (u32)__builtin_amdgcn_update_dpp((int)x, (int)x, 0x4E, 0xF, 0xF, false);
    else if constexpr (LM == 3)  return (u32)__builtin_amdgcn_update_dpp((int)x, (int)x, 0x1B, 0xF, 0xF, false);
    else if constexpr (LM == 7)  return (u32)__builtin_amdgcn_update_dpp((int)x, (int)x, 0x141, 0xF, 0xF, false);
    else if constexpr (LM == 8)  return (u32)__builtin_amdgcn_update_dpp((int)x, (int)x, 0x128, 0xF, 0xF, false);
    else if constexpr (LM == 15) return (u32)__builtin_amdgcn_update_dpp((int)x, (int)x, 0x140, 0xF, 0xF, false);
    else if constexpr (LM == 63) return (u32)__builtin_amdgcn_ds_bpermute(a63, (int)x);
    else                         return (u32)__builtin_amdgcn_ds_swizzle((int)x, 0x1F | (LM << 10));
}

// normalized bitonic sort of the 32 intra-lane elements (all static)
__device__ __forceinline__ void sortV(u32* e) {
    #pragma unroll
    for (int k = 2; k <= 32; k <<= 1) {
        #pragma unroll
        for (int v = 0; v < VV; v++) {
            int pv = v ^ (k - 1);
            if (v < pv) ceA(e[v], e[pv]);
        }
        #pragma unroll
        for (int j = k >> 2; j >= 1; j >>= 1)
            #pragma unroll
            for (int v = 0; v < VV; v++)
                if ((v & j) == 0) ceA(e[v], e[v | j]);
    }
}

__device__ __forceinline__ void clean16(u32* e) {
    #pragma unroll
    for (int j = 16; j >= 1; j >>= 1)
        #pragma unroll
        for (int v = 0; v < VV; v++)
            if ((v & j) == 0) ceA(e[v], e[v | j]);
}

template<int LM>
__device__ __forceinline__ void crossA(u32* e, bool keep, int a63) {
    #pragma unroll
    for (int v = 0; v < VV; v++) {
        u32 p = lxf<LM>(e[v], a63);
        e[v] = keep ? pk_min(e[v], p) : pk_max(e[v], p);
    }
}

template<int LM>
__device__ __forceinline__ void crossA_chain(u32* e, int lane, int a63) {
    crossA<LM>(e, (lane & LM) == 0, a63);
    if constexpr (LM > 1) crossA_chain<(LM >> 1)>(e, lane, a63);
}

template<int LM>
__device__ __forceinline__ void crossR(u32* e, bool keep, int a63) {
    #pragma unroll
    for (int v = 0; v < 16; v++) {
        const int w2 = v ^ 31;
        u32 p1 = lxf<LM>(e[w2], a63);
        u32 p2 = lxf<LM>(e[v], a63);
        e[v]  = keep ? pk_min(e[v],  p1) : pk_max(e[v],  p1);
        e[w2] = keep ? pk_min(e[w2], p2) : pk_max(e[w2], p2);
    }
}

template<int K>
__device__ __forceinline__ void level(u32* e, int lane, int a63) {
    crossR<(K >> 5) - 1>(e, (lane & (K >> 6)) == 0, a63);
    if constexpr (K >= 128) crossA_chain<(K >> 7)>(e, lane, a63);
    clean16(e);
}

// LDS column swizzle: phys = row ^ ((((row>>5)^g)&7)<<2)  (bits 2-4; bijective per column)
__device__ __forceinline__ int swz(int row, int g) {
    return row ^ ((((row >> 5) ^ g) & 7) << 2);
}

__global__ __launch_bounds__(512) void swd_kernel(const float* __restrict__ x,
                                                  const float* __restrict__ y,
                                                  const float* __restrict__ proj,
                                                  float* __restrict__ ws) {
    __shared__ __align__(16) u32 sbu[GG * NN];   // 64 KB: 8 columns of 2048 packed (x,y)

    const int tid = threadIdx.x;
    const int lane = tid & 63;
    const int w = tid >> 6;                    // wave id 0..7
    const int g16 = lane & 15;                 // MFMA n / m lane index
    const int kb = lane >> 4;                  // k-group 0..3
    const int blk = blockIdx.x;
    const int b = blk >> 10;                   // 1024 blocks per batch
    const int pbase = (blk & 1023) << 3;       // 8 proj rows per block

    // ---- B fragments (proj^T), k split kk=0 (dims 0..31) / kk=1 (dims 32..63)
    u32x4 bw0 = {0, 0, 0, 0}, bw1 = {0, 0, 0, 0};
    if (g16 < GG) {
        const float4* pr = (const float4*)(proj + (size_t)(pbase + g16) * DD);
        float4 f0 = pr[kb * 2], f1 = pr[kb * 2 + 1];
        bw0[0] = pk2u(f0.x, f0.y); bw0[1] = pk2u(f0.z, f0.w);
        bw0[2] = pk2u(f1.x, f1.y); bw0[3] = pk2u(f1.z, f1.w);
        float4 f2 = pr[8 + kb * 2], f3 = pr[8 + kb * 2 + 1];
        bw1[0] = pk2u(f2.x, f2.y); bw1[1] = pk2u(f2.z, f2.w);
        bw1[2] = pk2u(f3.x, f3.y); bw1[3] = pk2u(f3.z, f3.w);
    }
    const fh8 bf0 = __builtin_bit_cast(fh8, bw0);
    const fh8 bf1 = __builtin_bit_cast(fh8, bw1);

    const float* xb = x + (size_t)b * NN * DD;
    const float* yb = y + (size_t)b * NN * DD;

    auto aload = [&](const float* base, int rowbase, int kk) -> fh8 {
        const float4* ar = (const float4*)(base + (size_t)(rowbase + g16) * DD) + kk * 8 + kb * 2;
        float4 a0 = ar[0], a1 = ar[1];
        u32x4 t;
        t[0] = pk2u(a0.x, a0.y); t[1] = pk2u(a0.z, a0.w);
        t[2] = pk2u(a1.x, a1.y); t[3] = pk2u(a1.z, a1.w);
        return __builtin_bit_cast(fh8, t);
    };

    // ---- projection via MFMA: wave w covers rows w*256 .. +255 of both arrays
    #pragma unroll 2
    for (int t = 0; t < 16; t++) {
        const int rowbase = (w << 8) + (t << 4);
        f32x4 accx = {0.f, 0.f, 0.f, 0.f};
        f32x4 accy = {0.f, 0.f, 0.f, 0.f};
        accx = __builtin_amdgcn_mfma_f32_16x16x32_f16(aload(xb, rowbase, 0), bf0, accx, 0, 0, 0);
        accx = __builtin_amdgcn_mfma_f32_16x16x32_f16(aload(xb, rowbase, 1), bf1, accx, 0, 0, 0);
        accy = __builtin_amdgcn_mfma_f32_16x16x32_f16(aload(yb, rowbase, 0), bf0, accy, 0, 0, 0);
        accy = __builtin_amdgcn_mfma_f32_16x16x32_f16(aload(yb, rowbase, 1), bf1, accy, 0, 0, 0);
        // C layout (m89-verified): col g = lane&15, row = rowbase + (lane>>4)*4 + r
        if (g16 < GG) {
            const int R0 = rowbase + (kb << 2);            // 4-aligned
            u32x4 pk;
            #pragma unroll
            for (int r = 0; r < 4; r++)
                pk[r] = pk2u(accx[r], accy[r]);            // x -> lo, y -> hi
            // phys base = swz(R0) is 16B-aligned (xor touches bits 2-4 only)
            *(u32x4*)(sbu + (g16 << 11) + swz(R0, g16)) = pk;
        }
    }
    __syncthreads();

    // ---- sort: wave w sorts column g = w, fully wave-local (no barriers)
    const int a63 = (lane ^ 63) << 2;
    const int g = w;
    const u32* colbase = sbu + (g << 11) + (lane << 5);
    const int xm = (lane ^ g) & 7;             // readback chunk swizzle

    u32 e[VV];
    #pragma unroll
    for (int vb = 0; vb < 8; vb++) {
        uint4 tq = *(const uint4*)(colbase + ((vb ^ xm) << 2));
        e[(vb ^ xm) * 4 + 0] = tq.x; e[(vb ^ xm) * 4 + 1] = tq.y;
        e[(vb ^ xm) * 4 + 2] = tq.z; e[(vb ^ xm) * 4 + 3] = tq.w;
    }
    // note: e[vb'] holds logical chunk vb' = (vb^xm)^xm ... logical chunk c is at phys c^xm:
    // we iterated phys = vb^xm over all 8 values; stored into logical index (vb^xm) — wait:
    // logical chunk c lives at phys c^xm; loop reads phys (vb^xm) = logical ((vb^xm)^xm)=vb.
    // So the tq read above is logical chunk vb — store into e[vb*4+..]. Fix indices:
    // (rewritten correctly below)

    #pragma unroll
    for (int vb = 0; vb < 8; vb++) { /* no-op: indices fixed in the loop above is wrong; redo */ }

    // --- corrected readback (overwrites e fully) ---
    #pragma unroll
    for (int c = 0; c < 8; c++) {              // logical chunk c at phys c^xm
        uint4 tq = *(const uint4*)(colbase + ((c ^ xm) << 2));
        e[c * 4 + 0] = tq.x; e[c * 4 + 1] = tq.y;
        e[c * 4 + 2] = tq.z; e[c * 4 + 3] = tq.w;
    }

    sortV(e);                              // k = 2..32 (intra-lane)
    level<64>(e, lane, a63);
    level<128>(e, lane, a63);
    level<256>(e, lane, a63);
    level<512>(e, lane, a63);
    level<1024>(e, lane, a63);
    level<2048>(e, lane, a63);

    // sum of squared diffs: lo = sorted x-col, hi = sorted y-col
    float s = 0.f;
    #pragma unroll
    for (int v = 0; v < VV; v++) {
        h2 h = __builtin_bit_cast(h2, e[v]);
        float d = (float)h[0] - (float)h[1];
        s += d * d;
    }
    #pragma unroll
    for (int off = 32; off > 0; off >>= 1)
        s += __shfl_down(s, off, 64);
    if (lane == 0)
        atomicAdd(&ws[b * NSTRIPE + ((pbase + g) & (NSTRIPE - 1))], s);
}

__global__ void finalize_kernel(const float* __restrict__ ws, float* __restrict__ out) {
    __shared__ float red[256];
    int tid = threadIdx.x;
    for (int b = 0; b < BB; b++) {
        float s = 0.f;
        for (int i = tid; i < NSTRIPE; i += 256) s += ws[b * NSTRIPE + i];
        red[tid] = s;
        __syncthreads();
        for (int o = 128; o > 0; o >>= 1) {
            if (tid < o) red[tid] += red[tid + o];
            __syncthreads();
        }
        if (tid == 0) {
            float swd = red[0] / ((float)NN * (float)PP);
            out[b] = expf(-swd * swd * 0.5f);
        }
        __syncthreads();
    }
}

extern "C" void kernel_launch(void* const* d_in, const int* in_sizes, int n_in,
                              void* d_out, int out_size, void* d_ws, size_t ws_size,
                              hipStream_t stream) {
    const float* x = (const float*)d_in[0];
    const float* y = (const float*)d_in[1];
    const float* proj = (const float*)d_in[2];
    float* out = (float*)d_out;
    float* ws = (float*)d_ws;

    zero_ws_kernel<<<(BB * NSTRIPE + 255) / 256, 256, 0, stream>>>(ws);
    swd_kernel<<<BB * PP / GG, 512, 0, stream>>>(x, y, proj, ws);
    finalize_kernel<<<1, 256, 0, stream>>>(ws, out);
}